// Round 4
// baseline (482.599 us; speedup 1.0000x reference)
//
#include <hip/hip_runtime.h>
#include <hip/hip_bf16.h>

// ---------------------------------------------------------------------------
// CrossAttentionBlock: bilinear 3x upsample -> QKV 1x1 projections ->
// full cross-attention (N=9216, E=64, Co=32) -> 1x1 conv + BN + ReLU.
// Flash-style, fp16 MFMA 16x16x32, fp32 accumulate, no-max softmax
// (scores bounded), split-m partials combined additively in epilogue.
//
// R4 = R3 resubmitted (R3 hit GPUAcquisitionTimeout; never ran).
// ---------------------------------------------------------------------------

constexpr int B   = 2;
constexpr int N   = 9216;   // 96*96
constexpr int E   = 64;
constexpr int CO  = 32;
constexpr int CT  = 64;
constexpr int SPLIT  = 8;          // m-chunks per row-tile
constexpr int MCHUNK = N / SPLIT;  // 1152

typedef _Float16 f16x8 __attribute__((ext_vector_type(8)));
typedef float    f32x4 __attribute__((ext_vector_type(4)));

#define MFMA(a, b, c) __builtin_amdgcn_mfma_f32_16x16x32_f16((a), (b), (c), 0, 0, 0)

// exp(s/8) == exp2(s * SC); SC folded into Q projection weights.
#define SC 0.18033688011112042f

// ---------------------------------------------------------------------------
// Kernel 1: bilinear upsample (half-pixel, clamped) + Q projection.
// Q stored [B][N][E] fp16, PRE-SCALED by SC. One thread per output pixel.
// ---------------------------------------------------------------------------
__global__ __launch_bounds__(256) void proj_q_kernel(
    const float* __restrict__ xt,   // [B][64][32][32]
    const float* __restrict__ qw,   // [64][64]
    const float* __restrict__ qb,   // [64]
    _Float16* __restrict__ Q)
{
  const int p  = blockIdx.x * 256 + threadIdx.x;   // 0..18431
  const int b  = p / N, n = p % N;
  const int ho = n / 96, wo = n % 96;

  const float sh = (ho + 0.5f) * (1.0f / 3.0f) - 0.5f;
  const float sw = (wo + 0.5f) * (1.0f / 3.0f) - 0.5f;
  int h0 = (int)floorf(sh); const float fh = sh - (float)h0;
  int w0 = (int)floorf(sw); const float fw = sw - (float)w0;
  int h1 = min(h0 + 1, 31); h0 = max(h0, 0);
  int w1 = min(w0 + 1, 31); w0 = max(w0, 0);

  const float c00 = (1.f - fh) * (1.f - fw), c01 = (1.f - fh) * fw;
  const float c10 = fh * (1.f - fw),         c11 = fh * fw;
  const int i00 = h0 * 32 + w0, i01 = h0 * 32 + w1;
  const int i10 = h1 * 32 + w0, i11 = h1 * 32 + w1;

  const float* xb = xt + (size_t)b * 64 * 1024;
  float xup[64];
#pragma unroll
  for (int c = 0; c < 64; ++c) {
    const float* xc = xb + (size_t)c * 1024;
    xup[c] = xc[i00] * c00 + xc[i01] * c01 + xc[i10] * c10 + xc[i11] * c11;
  }

  _Float16* Qp = Q + (size_t)p * E;
  for (int e0 = 0; e0 < 64; e0 += 8) {
    union { _Float16 h[8]; uint4 v; } pk;
#pragma unroll
    for (int j = 0; j < 8; ++j) {
      const int e = e0 + j;
      float acc = qb[e];
#pragma unroll
      for (int c = 0; c < 64; ++c) acc += xup[c] * qw[e * 64 + c];
      pk.h[j] = (_Float16)(acc * SC);
    }
    *(uint4*)(Qp + e0) = pk.v;
  }
}

// ---------------------------------------------------------------------------
// Kernel 2: K and V projections from x_optical.
// K stored [B][N][E] fp16; V stored transposed [B][CO][N] fp16.
// ---------------------------------------------------------------------------
__global__ __launch_bounds__(256) void proj_kv_kernel(
    const float* __restrict__ xo,   // [B][32][N]
    const float* __restrict__ kw, const float* __restrict__ kb,
    const float* __restrict__ vw, const float* __restrict__ vb,
    _Float16* __restrict__ K, _Float16* __restrict__ Vt)
{
  const int p = blockIdx.x * 256 + threadIdx.x;
  const int b = p / N, n = p % N;

  const float* xb = xo + (size_t)b * CO * N + n;
  float x[32];
#pragma unroll
  for (int c = 0; c < 32; ++c) x[c] = xb[(size_t)c * N];

  _Float16* Kp = K + (size_t)p * E;
  for (int e0 = 0; e0 < 64; e0 += 8) {
    union { _Float16 h[8]; uint4 v; } pk;
#pragma unroll
    for (int j = 0; j < 8; ++j) {
      const int e = e0 + j;
      float acc = kb[e];
#pragma unroll
      for (int c = 0; c < 32; ++c) acc += x[c] * kw[e * 32 + c];
      pk.h[j] = (_Float16)acc;
    }
    *(uint4*)(Kp + e0) = pk.v;
  }

  _Float16* Vp = Vt + (size_t)b * CO * N + n;
#pragma unroll
  for (int o = 0; o < 32; ++o) {
    float acc = vb[o];
#pragma unroll
    for (int c = 0; c < 32; ++c) acc += x[c] * vw[o * 32 + c];
    Vp[(size_t)o * N] = (_Float16)acc;
  }
}

// ---------------------------------------------------------------------------
// Kernel 3: flash attention partials. 16 Q-rows per wave, one m-chunk.
// Swapped QK^T: S^T = mfma(A=K-frag, B=Q-frag); lane holds S^T[m=4g+i][n=l&15].
// P^T B-fragment for PV assembled via 8 shfl per 32-m step.
// ---------------------------------------------------------------------------
__global__ __launch_bounds__(256) void attn_kernel(
    const _Float16* __restrict__ Q,
    const _Float16* __restrict__ K,
    const _Float16* __restrict__ Vt,
    float* __restrict__ OutWS,   // [SPLIT][B][N][CO]
    float* __restrict__ SumWS)   // [SPLIT][B][N]
{
  const int tid  = threadIdx.x;
  const int wave = tid >> 6, lane = tid & 63;
  const int r16  = lane & 15, g = lane >> 4;

  const int work  = blockIdx.x;
  const int chunk = work & (SPLIT - 1);
  const int t64   = work >> 3;            // 0..287
  const int b     = t64 / 144;
  const int rowbase = (t64 % 144) * 64 + wave * 16;

  const _Float16* Qb = Q  + ((size_t)b * N + rowbase) * E;
  const _Float16* Kb = K  + (size_t)b * N * E;
  const _Float16* Vb = Vt + (size_t)b * CO * N;

  // Q B-fragments: 2 k-steps (contiguous 16B per lane)
  f16x8 qf[2];
#pragma unroll
  for (int ks = 0; ks < 2; ++ks)
    qf[ks] = *(const f16x8*)(Qb + r16 * E + ks * 32 + g * 8);

  f32x4 oacc[2];
  oacc[0] = (f32x4){0.f, 0.f, 0.f, 0.f};
  oacc[1] = (f32x4){0.f, 0.f, 0.f, 0.f};
  float sume = 0.f;

  // shfl sources for P^T fragment exchange
  const int srcLo = r16 + 32 * (g & 1);
  const int srcHi = srcLo + 16;
  const bool selLo = (g < 2);

  const int mstart = chunk * MCHUNK;
  for (int m = mstart; m < mstart + MCHUNK; m += 32) {
    f16x8 kf[2][2];
#pragma unroll
    for (int mt = 0; mt < 2; ++mt)
#pragma unroll
      for (int ks = 0; ks < 2; ++ks)
        kf[mt][ks] = *(const f16x8*)(Kb + (size_t)(m + mt * 16 + r16) * E + ks * 32 + g * 8);
    f16x8 vf[2];
#pragma unroll
    for (int ot = 0; ot < 2; ++ot)
      vf[ot] = *(const f16x8*)(Vb + (size_t)(ot * 16 + r16) * N + m + g * 8);

    // S^T tiles: tile0 m-local 0-15, tile1 16-31; cols n
    f32x4 s0 = (f32x4){0.f, 0.f, 0.f, 0.f};
    f32x4 s1 = (f32x4){0.f, 0.f, 0.f, 0.f};
    s0 = MFMA(kf[0][0], qf[0], s0);
    s0 = MFMA(kf[0][1], qf[1], s0);
    s1 = MFMA(kf[1][0], qf[0], s1);
    s1 = MFMA(kf[1][1], qf[1], s1);

    float p0[4], p1[4];
#pragma unroll
    for (int i = 0; i < 4; ++i) {
      p0[i] = __builtin_amdgcn_exp2f(s0[i]);   // SC pre-folded into Q
      p1[i] = __builtin_amdgcn_exp2f(s1[i]);
    }
    sume += p0[0] + p0[1] + p0[2] + p0[3]
          + p1[0] + p1[1] + p1[2] + p1[3];

    // pack pairs (m, m+1) -> u32 of 2 fp16 (RTZ pack, single instr)
    const unsigned pk00 = __builtin_bit_cast(unsigned, __builtin_amdgcn_cvt_pkrtz(p0[0], p0[1]));
    const unsigned pk01 = __builtin_bit_cast(unsigned, __builtin_amdgcn_cvt_pkrtz(p0[2], p0[3]));
    const unsigned pk10 = __builtin_bit_cast(unsigned, __builtin_amdgcn_cvt_pkrtz(p1[0], p1[1]));
    const unsigned pk11 = __builtin_bit_cast(unsigned, __builtin_amdgcn_cvt_pkrtz(p1[2], p1[3]));

    // B-frag word w holds P^T(m=8g+2w..+1, n=l&15); tile select by g>>1
    const unsigned w0a = __shfl(pk00, srcLo), w0b = __shfl(pk10, srcLo);
    const unsigned w1a = __shfl(pk01, srcLo), w1b = __shfl(pk11, srcLo);
    const unsigned w2a = __shfl(pk00, srcHi), w2b = __shfl(pk10, srcHi);
    const unsigned w3a = __shfl(pk01, srcHi), w3b = __shfl(pk11, srcHi);
    union { unsigned u[4]; f16x8 v; } pb;
    pb.u[0] = selLo ? w0a : w0b;
    pb.u[1] = selLo ? w1a : w1b;
    pb.u[2] = selLo ? w2a : w2b;
    pb.u[3] = selLo ? w3a : w3b;

    // out^T[o][n] += Vt-frag * P^T-frag
    oacc[0] = MFMA(vf[0], pb.v, oacc[0]);
    oacc[1] = MFMA(vf[1], pb.v, oacc[1]);
  }

  // reduce sumexp across the four 16-lane groups (each held different m)
  sume += __shfl_xor(sume, 16);
  sume += __shfl_xor(sume, 32);

  float* OW = OutWS + (size_t)(chunk * B + b) * N * CO;
  float* SW = SumWS + (size_t)(chunk * B + b) * N;
  const int n = rowbase + r16;
  if (g == 0) SW[n] = sume;
#pragma unroll
  for (int ot = 0; ot < 2; ++ot)
#pragma unroll
    for (int i = 0; i < 4; ++i)
      OW[(size_t)n * CO + ot * 16 + 4 * g + i] = oacc[ot][i];
}

// ---------------------------------------------------------------------------
// Kernel 4: combine split-m partials, normalize, out_w conv, BN, ReLU.
// Block: 64 pixels x 4 split-groups. Phase 1: each group sums 2 splits with
// dense float4 reads (wave reads contiguous 8KB). LDS reduce (stride-33 pad,
// conflict-free). Phase 2: each group computes 16 t-outputs, coalesced store.
// ---------------------------------------------------------------------------
__global__ __launch_bounds__(256) void epi_kernel(
    const float* __restrict__ OutWS, const float* __restrict__ SumWS,
    const float* __restrict__ ow, const float* __restrict__ gamma,
    const float* __restrict__ beta, const float* __restrict__ mean,
    const float* __restrict__ var, float* __restrict__ out)
{
  __shared__ float part[4][64][33];
  __shared__ float psum[4][64];

  const int tid  = threadIdx.x;
  const int nloc = tid & 63, grp = tid >> 6;     // grp: split-group / t-group
  const int pix  = blockIdx.x * 64 + nloc;
  const int b    = pix / N, n = pix % N;

  // phase 1: partial accumulation over this group's 2 splits
  f32x4 acc[8];
#pragma unroll
  for (int j = 0; j < 8; ++j) acc[j] = (f32x4){0.f, 0.f, 0.f, 0.f};
  float ssum = 0.f;
#pragma unroll
  for (int k = 0; k < 2; ++k) {
    const int sc = grp * 2 + k;
    const f32x4* src = (const f32x4*)(OutWS + ((size_t)(sc * B + b) * N + n) * CO);
#pragma unroll
    for (int j = 0; j < 8; ++j) acc[j] += src[j];
    ssum += SumWS[(size_t)(sc * B + b) * N + n];
  }
#pragma unroll
  for (int j = 0; j < 8; ++j)
#pragma unroll
    for (int i = 0; i < 4; ++i)
      part[grp][nloc][j * 4 + i] = acc[j][i];
  psum[grp][nloc] = ssum;
  __syncthreads();

  // phase 2: full reduce + normalize
  const float s = psum[0][nloc] + psum[1][nloc] + psum[2][nloc] + psum[3][nloc];
  const float inv = 1.f / s;
  float onr[CO];
#pragma unroll
  for (int o = 0; o < CO; ++o)
    onr[o] = (part[0][nloc][o] + part[1][nloc][o] +
              part[2][nloc][o] + part[3][nloc][o]) * inv;

  // out conv + BN + ReLU; grp selects t = grp + 4*i (wave-uniform t)
#pragma unroll
  for (int i = 0; i < 16; ++i) {
    const int t = grp + 4 * i;
    float acc2 = 0.f;
#pragma unroll
    for (int o = 0; o < CO; ++o) acc2 += onr[o] * ow[t * CO + o];
    const float scl = gamma[t] * rsqrtf(var[t] + 1e-5f);
    const float bia = beta[t] - mean[t] * scl;
    const float gv  = acc2 * scl + bia;
    out[(size_t)(b * CT + t) * N + n] = fmaxf(gv, 0.f);
  }
}

// ---------------------------------------------------------------------------
extern "C" void kernel_launch(void* const* d_in, const int* in_sizes, int n_in,
                              void* d_out, int out_size, void* d_ws, size_t ws_size,
                              hipStream_t stream) {
  const float* xt = (const float*)d_in[0];
  const float* xo = (const float*)d_in[1];
  const float* qw = (const float*)d_in[2];
  const float* qb = (const float*)d_in[3];
  const float* kw = (const float*)d_in[4];
  const float* kb = (const float*)d_in[5];
  const float* vw = (const float*)d_in[6];
  const float* vb = (const float*)d_in[7];
  const float* ow = (const float*)d_in[8];
  const float* gm = (const float*)d_in[9];
  const float* bt = (const float*)d_in[10];
  const float* mn = (const float*)d_in[11];
  const float* vr = (const float*)d_in[12];

  char* ws = (char*)d_ws;
  _Float16* Qd  = (_Float16*)ws;  ws += (size_t)B * N * E * 2;          // 2.36 MB
  _Float16* Kd  = (_Float16*)ws;  ws += (size_t)B * N * E * 2;          // 2.36 MB
  _Float16* Vtd = (_Float16*)ws;  ws += (size_t)B * CO * N * 2;         // 1.18 MB
  float* OutWS  = (float*)ws;     ws += (size_t)SPLIT * B * N * CO * 4; // 18.9 MB
  float* SumWS  = (float*)ws;                                           // 0.6 MB

  proj_q_kernel<<<(B * N) / 256, 256, 0, stream>>>(xt, qw, qb, Qd);
  proj_kv_kernel<<<(B * N) / 256, 256, 0, stream>>>(xo, kw, kb, vw, vb, Kd, Vtd);
  attn_kernel<<<(N / 64) * B * SPLIT, 256, 0, stream>>>(Qd, Kd, Vtd, OutWS, SumWS);
  epi_kernel<<<(B * N) / 64, 256, 0, stream>>>(OutWS, SumWS, ow, gm, bt, mn, vr,
                                               (float*)d_out);
}

// Round 5
// 438.589 us; speedup vs baseline: 1.1003x; 1.1003x over previous
//
#include <hip/hip_runtime.h>
#include <hip/hip_bf16.h>

// ---------------------------------------------------------------------------
// CrossAttentionBlock: bilinear 3x upsample -> QKV 1x1 projections ->
// full cross-attention (N=9216, E=64, Co=32) -> 1x1 conv + BN + ReLU.
// Flash-style, fp16 MFMA 16x16x32, fp32 accumulate, no-max softmax
// (scores bounded), split-m partials combined additively in epilogue.
//
// R5 changes vs R4 (which regressed 136->276 us: per-iteration-bound):
//  - PV step shuffle-FREE: exploit MFMA k-permutation freedom. k-slot s=8g+j
//    maps to m_local = 4g+j (j<4) / 16+4g+(j-4) (j>=4), so each lane's PV
//    B-fragment is its OWN packed exp values. V-frag split into 2x8B loads.
//  - rows=32/wave (R1-proven fragment math).
//  - SPLIT=16 when ws_size permits (runtime-constant branch), else 8.
//  - __launch_bounds__(256,6) for ~6 waves/SIMD residency; unroll-2 m-loop.
// ---------------------------------------------------------------------------

constexpr int B   = 2;
constexpr int N   = 9216;   // 96*96
constexpr int E   = 64;
constexpr int CO  = 32;
constexpr int CT  = 64;

typedef _Float16 f16x8 __attribute__((ext_vector_type(8)));
typedef _Float16 f16x4 __attribute__((ext_vector_type(4)));
typedef float    f32x4 __attribute__((ext_vector_type(4)));

#define MFMA(a, b, c) __builtin_amdgcn_mfma_f32_16x16x32_f16((a), (b), (c), 0, 0, 0)

// exp(s/8) == exp2(s * SC); SC folded into Q projection weights.
#define SC 0.18033688011112042f

// ---------------------------------------------------------------------------
// Kernel 1: bilinear upsample (half-pixel, clamped) + Q projection.
// Q stored [B][N][E] fp16, PRE-SCALED by SC. One thread per output pixel.
// ---------------------------------------------------------------------------
__global__ __launch_bounds__(256) void proj_q_kernel(
    const float* __restrict__ xt,   // [B][64][32][32]
    const float* __restrict__ qw,   // [64][64]
    const float* __restrict__ qb,   // [64]
    _Float16* __restrict__ Q)
{
  const int p  = blockIdx.x * 256 + threadIdx.x;   // 0..18431
  const int b  = p / N, n = p % N;
  const int ho = n / 96, wo = n % 96;

  const float sh = (ho + 0.5f) * (1.0f / 3.0f) - 0.5f;
  const float sw = (wo + 0.5f) * (1.0f / 3.0f) - 0.5f;
  int h0 = (int)floorf(sh); const float fh = sh - (float)h0;
  int w0 = (int)floorf(sw); const float fw = sw - (float)w0;
  int h1 = min(h0 + 1, 31); h0 = max(h0, 0);
  int w1 = min(w0 + 1, 31); w0 = max(w0, 0);

  const float c00 = (1.f - fh) * (1.f - fw), c01 = (1.f - fh) * fw;
  const float c10 = fh * (1.f - fw),         c11 = fh * fw;
  const int i00 = h0 * 32 + w0, i01 = h0 * 32 + w1;
  const int i10 = h1 * 32 + w0, i11 = h1 * 32 + w1;

  const float* xb = xt + (size_t)b * 64 * 1024;
  float xup[64];
#pragma unroll
  for (int c = 0; c < 64; ++c) {
    const float* xc = xb + (size_t)c * 1024;
    xup[c] = xc[i00] * c00 + xc[i01] * c01 + xc[i10] * c10 + xc[i11] * c11;
  }

  _Float16* Qp = Q + (size_t)p * E;
  for (int e0 = 0; e0 < 64; e0 += 8) {
    union { _Float16 h[8]; uint4 v; } pk;
#pragma unroll
    for (int j = 0; j < 8; ++j) {
      const int e = e0 + j;
      float acc = qb[e];
#pragma unroll
      for (int c = 0; c < 64; ++c) acc += xup[c] * qw[e * 64 + c];
      pk.h[j] = (_Float16)(acc * SC);
    }
    *(uint4*)(Qp + e0) = pk.v;
  }
}

// ---------------------------------------------------------------------------
// Kernel 2: K and V projections from x_optical.
// K stored [B][N][E] fp16; V stored transposed [B][CO][N] fp16.
// ---------------------------------------------------------------------------
__global__ __launch_bounds__(256) void proj_kv_kernel(
    const float* __restrict__ xo,   // [B][32][N]
    const float* __restrict__ kw, const float* __restrict__ kb,
    const float* __restrict__ vw, const float* __restrict__ vb,
    _Float16* __restrict__ K, _Float16* __restrict__ Vt)
{
  const int p = blockIdx.x * 256 + threadIdx.x;
  const int b = p / N, n = p % N;

  const float* xb = xo + (size_t)b * CO * N + n;
  float x[32];
#pragma unroll
  for (int c = 0; c < 32; ++c) x[c] = xb[(size_t)c * N];

  _Float16* Kp = K + (size_t)p * E;
  for (int e0 = 0; e0 < 64; e0 += 8) {
    union { _Float16 h[8]; uint4 v; } pk;
#pragma unroll
    for (int j = 0; j < 8; ++j) {
      const int e = e0 + j;
      float acc = kb[e];
#pragma unroll
      for (int c = 0; c < 32; ++c) acc += x[c] * kw[e * 32 + c];
      pk.h[j] = (_Float16)acc;
    }
    *(uint4*)(Kp + e0) = pk.v;
  }

  _Float16* Vp = Vt + (size_t)b * CO * N + n;
#pragma unroll
  for (int o = 0; o < 32; ++o) {
    float acc = vb[o];
#pragma unroll
    for (int c = 0; c < 32; ++c) acc += x[c] * vw[o * 32 + c];
    Vp[(size_t)o * N] = (_Float16)acc;
  }
}

// ---------------------------------------------------------------------------
// Kernel 3: flash attention partials. 32 Q-rows per wave, one m-chunk.
// Swapped QK^T: S^T = mfma(A=K, B=Q); lane (r16,g) holds S^T[m=4g+i][n=r16]
// for tile0 (m_local 0..15) and tile1 (16..31).
// PV uses a permuted k-slot mapping s=8g+j -> m_local = 4g+j (j<4),
// 16+4g+(j-4) (j>=4): lane's B-frag = its own packed exps (NO shuffles);
// V A-frag loaded with the same mapping (two 8B loads per o-tile).
// ---------------------------------------------------------------------------
template<int SPLIT>
__global__ __launch_bounds__(256, 6) void attn_kernel(
    const _Float16* __restrict__ Q,
    const _Float16* __restrict__ K,
    const _Float16* __restrict__ Vt,
    float* __restrict__ OutWS,   // [SPLIT][B][N][CO]
    float* __restrict__ SumWS)   // [SPLIT][B][N]
{
  constexpr int MCHUNK = N / SPLIT;
  const int tid  = threadIdx.x;
  const int wave = tid >> 6, lane = tid & 63;
  const int r16  = lane & 15, g = lane >> 4;

  const int work  = blockIdx.x;
  const int chunk = work & (SPLIT - 1);
  const int tb    = work / SPLIT;          // 0..143
  const int b     = tb / 72;
  const int rowbase = (tb % 72) * 128 + wave * 32;

  const _Float16* Qb = Q  + ((size_t)b * N + rowbase) * E;
  const _Float16* Kb = K  + (size_t)b * N * E;
  const _Float16* Vb = Vt + (size_t)b * CO * N;

  // Q B-fragments: 2 row-tiles x 2 k-steps (contiguous 16B per lane)
  f16x8 qf[2][2];
#pragma unroll
  for (int rt = 0; rt < 2; ++rt)
#pragma unroll
    for (int ks = 0; ks < 2; ++ks)
      qf[rt][ks] = *(const f16x8*)(Qb + (rt * 16 + r16) * E + ks * 32 + g * 8);

  f32x4 oacc[2][2];
#pragma unroll
  for (int a = 0; a < 2; ++a)
#pragma unroll
    for (int c = 0; c < 2; ++c) oacc[a][c] = (f32x4){0.f, 0.f, 0.f, 0.f};
  float sume[2] = {0.f, 0.f};

  const int mstart = chunk * MCHUNK;
#pragma unroll 2
  for (int m = mstart; m < mstart + MCHUNK; m += 32) {
    // K A-fragments: 2 m-tiles x 2 k-steps
    f16x8 kf[2][2];
#pragma unroll
    for (int mt = 0; mt < 2; ++mt)
#pragma unroll
      for (int ks = 0; ks < 2; ++ks)
        kf[mt][ks] = *(const f16x8*)(Kb + (size_t)(m + mt * 16 + r16) * E + ks * 32 + g * 8);

    // V A-fragments with permuted k-slots: elem j<4 -> m_local 4g+j,
    // j>=4 -> m_local 16+4g+(j-4). Two 8B loads per o-tile.
    union { f16x4 h[2]; f16x8 v; } vf[2];
#pragma unroll
    for (int ot = 0; ot < 2; ++ot) {
      const _Float16* vp = Vb + (size_t)(ot * 16 + r16) * N + m + 4 * g;
      vf[ot].h[0] = *(const f16x4*)(vp);
      vf[ot].h[1] = *(const f16x4*)(vp + 16);
    }

#pragma unroll
    for (int rt = 0; rt < 2; ++rt) {
      // S^T tiles: tile0 m_local 0-15, tile1 16-31; cols n
      f32x4 s0 = (f32x4){0.f, 0.f, 0.f, 0.f};
      f32x4 s1 = (f32x4){0.f, 0.f, 0.f, 0.f};
      s0 = MFMA(kf[0][0], qf[rt][0], s0);
      s0 = MFMA(kf[0][1], qf[rt][1], s0);
      s1 = MFMA(kf[1][0], qf[rt][0], s1);
      s1 = MFMA(kf[1][1], qf[rt][1], s1);

      float p0[4], p1[4];
#pragma unroll
      for (int i = 0; i < 4; ++i) {
        p0[i] = __builtin_amdgcn_exp2f(s0[i]);   // SC pre-folded into Q
        p1[i] = __builtin_amdgcn_exp2f(s1[i]);
      }
      sume[rt] += p0[0] + p0[1] + p0[2] + p0[3]
                + p1[0] + p1[1] + p1[2] + p1[3];

      // PV B-frag: lane's own values, permuted-k order (NO shuffles).
      union { unsigned u[4]; f16x8 v; } pb;
      pb.u[0] = __builtin_bit_cast(unsigned, __builtin_amdgcn_cvt_pkrtz(p0[0], p0[1]));
      pb.u[1] = __builtin_bit_cast(unsigned, __builtin_amdgcn_cvt_pkrtz(p0[2], p0[3]));
      pb.u[2] = __builtin_bit_cast(unsigned, __builtin_amdgcn_cvt_pkrtz(p1[0], p1[1]));
      pb.u[3] = __builtin_bit_cast(unsigned, __builtin_amdgcn_cvt_pkrtz(p1[2], p1[3]));

      // out^T[o][n] += V-frag * P^T-frag
      oacc[rt][0] = MFMA(vf[0].v, pb.v, oacc[rt][0]);
      oacc[rt][1] = MFMA(vf[1].v, pb.v, oacc[rt][1]);
    }
  }

  // reduce sumexp across the four 16-lane groups (each held different m)
#pragma unroll
  for (int rt = 0; rt < 2; ++rt) {
    sume[rt] += __shfl_xor(sume[rt], 16);
    sume[rt] += __shfl_xor(sume[rt], 32);
  }

  float* OW = OutWS + (size_t)(chunk * B + b) * N * CO;
  float* SW = SumWS + (size_t)(chunk * B + b) * N;
#pragma unroll
  for (int rt = 0; rt < 2; ++rt) {
    const int n = rowbase + rt * 16 + r16;
    if (g == 0) SW[n] = sume[rt];
#pragma unroll
    for (int ot = 0; ot < 2; ++ot)
#pragma unroll
      for (int i = 0; i < 4; ++i)
        OW[(size_t)n * CO + ot * 16 + 4 * g + i] = oacc[rt][ot][i];
  }
}

// ---------------------------------------------------------------------------
// Kernel 4: combine split-m partials, normalize, out_w conv, BN, ReLU.
// Block: 64 pixels x 4 split-groups, dense float4 reads, LDS reduce.
// ---------------------------------------------------------------------------
template<int SPLIT>
__global__ __launch_bounds__(256) void epi_kernel(
    const float* __restrict__ OutWS, const float* __restrict__ SumWS,
    const float* __restrict__ ow, const float* __restrict__ gamma,
    const float* __restrict__ beta, const float* __restrict__ mean,
    const float* __restrict__ var, float* __restrict__ out)
{
  __shared__ float part[4][64][33];
  __shared__ float psum[4][64];

  const int tid  = threadIdx.x;
  const int nloc = tid & 63, grp = tid >> 6;     // grp: split-group / t-group
  const int pix  = blockIdx.x * 64 + nloc;
  const int b    = pix / N, n = pix % N;

  // phase 1: partial accumulation over this group's SPLIT/4 splits
  f32x4 acc[8];
#pragma unroll
  for (int j = 0; j < 8; ++j) acc[j] = (f32x4){0.f, 0.f, 0.f, 0.f};
  float ssum = 0.f;
#pragma unroll
  for (int k = 0; k < SPLIT / 4; ++k) {
    const int sc = grp * (SPLIT / 4) + k;
    const f32x4* src = (const f32x4*)(OutWS + ((size_t)(sc * B + b) * N + n) * CO);
#pragma unroll
    for (int j = 0; j < 8; ++j) acc[j] += src[j];
    ssum += SumWS[(size_t)(sc * B + b) * N + n];
  }
#pragma unroll
  for (int j = 0; j < 8; ++j)
#pragma unroll
    for (int i = 0; i < 4; ++i)
      part[grp][nloc][j * 4 + i] = acc[j][i];
  psum[grp][nloc] = ssum;
  __syncthreads();

  // phase 2: full reduce + normalize
  const float s = psum[0][nloc] + psum[1][nloc] + psum[2][nloc] + psum[3][nloc];
  const float inv = 1.f / s;
  float onr[CO];
#pragma unroll
  for (int o = 0; o < CO; ++o)
    onr[o] = (part[0][nloc][o] + part[1][nloc][o] +
              part[2][nloc][o] + part[3][nloc][o]) * inv;

  // out conv + BN + ReLU; grp selects t = grp + 4*i (wave-uniform t)
#pragma unroll
  for (int i = 0; i < 16; ++i) {
    const int t = grp + 4 * i;
    float acc2 = 0.f;
#pragma unroll
    for (int o = 0; o < CO; ++o) acc2 += onr[o] * ow[t * CO + o];
    const float scl = gamma[t] * rsqrtf(var[t] + 1e-5f);
    const float bia = beta[t] - mean[t] * scl;
    const float gv  = acc2 * scl + bia;
    out[(size_t)(b * CT + t) * N + n] = fmaxf(gv, 0.f);
  }
}

// ---------------------------------------------------------------------------
extern "C" void kernel_launch(void* const* d_in, const int* in_sizes, int n_in,
                              void* d_out, int out_size, void* d_ws, size_t ws_size,
                              hipStream_t stream) {
  const float* xt = (const float*)d_in[0];
  const float* xo = (const float*)d_in[1];
  const float* qw = (const float*)d_in[2];
  const float* qb = (const float*)d_in[3];
  const float* kw = (const float*)d_in[4];
  const float* kb = (const float*)d_in[5];
  const float* vw = (const float*)d_in[6];
  const float* vb = (const float*)d_in[7];
  const float* ow = (const float*)d_in[8];
  const float* gm = (const float*)d_in[9];
  const float* bt = (const float*)d_in[10];
  const float* mn = (const float*)d_in[11];
  const float* vr = (const float*)d_in[12];

  char* ws = (char*)d_ws;
  _Float16* Qd  = (_Float16*)ws;  ws += (size_t)B * N * E * 2;   // 2.36 MB
  _Float16* Kd  = (_Float16*)ws;  ws += (size_t)B * N * E * 2;   // 2.36 MB
  _Float16* Vtd = (_Float16*)ws;  ws += (size_t)B * CO * N * 2;  // 1.18 MB
  float* OutWS  = (float*)ws;     // SPLIT*B*N*CO*4
  const size_t base = (size_t)B * N * E * 2 * 2 + (size_t)B * CO * N * 2;
  const size_t need16 = base + (size_t)16 * B * N * (CO + 1) * 4;  // 44.8 MB

  proj_q_kernel<<<(B * N) / 256, 256, 0, stream>>>(xt, qw, qb, Qd);
  proj_kv_kernel<<<(B * N) / 256, 256, 0, stream>>>(xo, kw, kb, vw, vb, Kd, Vtd);

  if (ws_size >= need16) {
    float* SumWS = OutWS + (size_t)16 * B * N * CO;
    attn_kernel<16><<<72 * B * 16, 256, 0, stream>>>(Qd, Kd, Vtd, OutWS, SumWS);
    epi_kernel<16><<<(B * N) / 64, 256, 0, stream>>>(OutWS, SumWS, ow, gm, bt, mn, vr,
                                                     (float*)d_out);
  } else {
    float* SumWS = OutWS + (size_t)8 * B * N * CO;
    attn_kernel<8><<<72 * B * 8, 256, 0, stream>>>(Qd, Kd, Vtd, OutWS, SumWS);
    epi_kernel<8><<<(B * N) / 64, 256, 0, stream>>>(OutWS, SumWS, ow, gm, bt, mn, vr,
                                                    (float*)d_out);
  }
}